// Round 9
// baseline (393.824 us; speedup 1.0000x reference)
//
#include <hip/hip_runtime.h>
#include <hip/hip_bf16.h>

#define HS 128
#define NVT 32
#define NN 256

typedef __attribute__((ext_vector_type(8))) short bf16x8;
typedef __attribute__((ext_vector_type(4))) short s16x4;
typedef __attribute__((ext_vector_type(4))) float f32x4;
typedef __attribute__((ext_vector_type(4))) unsigned int u32x4;

// ws layout (bytes):
//   [0, 32768)       TABB bf16 [512][32]: rows 0..383 = GW[t][g] at [g][t]; rows 384..511 = G[t][h] at [384+h][t]
//   [32768, 65536)   GIT2 bf16 [32][128][4]: {gi_r+b, gi_z+b, gi_n, 0}
//   [65536, 4259840) cnt u32 [512][256][8]  packed-byte type counts
#define TABB_OFF 0
#define GIT2_OFF 32768
#define CNT_OFF  65536

static __device__ __forceinline__ short f2bs(float f) {
    __hip_bfloat16 h = __float2bfloat16(f);
    short s; __builtin_memcpy(&s, &h, 2);
    return s;
}
static __device__ __forceinline__ float bs2f(short s) {
    __hip_bfloat16 h; __builtin_memcpy(&h, &s, 2);
    return __bfloat162float(h);
}
static __device__ __forceinline__ float sigm(float x) {
    return __builtin_amdgcn_rcpf(1.f + __expf(-x));
}

// ---------------- Kernel Z: zero the atomic cnt buffer ----------------------
__global__ void __launch_bounds__(256) zero_cnt(uint4* __restrict__ p) {
    p[blockIdx.x * 256 + threadIdx.x] = make_uint4(0, 0, 0, 0);
}

// ---------------- Kernel A: tiny tables (fp32 inputs) -----------------------
__global__ void __launch_bounds__(512) build_tables(
    const float* __restrict__ W_ih, const float* __restrict__ W_hh,
    const float* __restrict__ b_ih, const float* __restrict__ b_hh,
    const float* __restrict__ Wg,   const float* __restrict__ bg,
    const float* __restrict__ Wm,
    short* __restrict__ TABB, short* __restrict__ GIT2)
{
    __shared__ float G_s[HS];
    const int t = blockIdx.x;
    const int j = threadIdx.x;
    if (j < HS) {
        float x = Wg[j * NVT + t] + bg[j];
        G_s[j] = sigm(x) * Wm[j * NVT + t];
    }
    __syncthreads();
    if (j < 384) {
        float acc = 0.f;
        for (int h = 0; h < HS; ++h) acc += G_s[h] * W_hh[j * HS + h];
        TABB[j * NVT + t] = f2bs(acc);
        float git = W_ih[j * NVT + t] + b_ih[j];
        int gate = j >> 7, h = j & 127;
        if (gate < 2) git += b_hh[j];                 // fold b_hh for r,z only
        GIT2[(t * 128 + h) * 4 + gate] = f2bs(git);
    } else {
        TABB[j * NVT + t] = f2bs(G_s[j - 384]);       // G[t][h] at [384+h][t]
        GIT2[(t * 128 + (j - 384)) * 4 + 3] = 0;      // pad lane
    }
}

// ---------------- Kernel H: streaming histogram, barrier-free loads ---------
// 4096 blocks = 512 graphs x 8 bands (32 rows). Wave w owns rows band*32+w*8..+8;
// lane l owns columns 4l..4l+3. 8 independent uint4 loads per thread, no
// load->barrier->consume cycle anywhere.
__global__ void __launch_bounds__(256) hist(
    const int* __restrict__ node_types, const int* __restrict__ adj,
    unsigned* __restrict__ cnt)
{
    __shared__ unsigned pc[4][8][NN];     // 32 KB [wave][q][col]
    const int blk = blockIdx.x;
    const int b = blk & 511, band = blk >> 9;     // consecutive blocks -> different graphs
    const int tid = threadIdx.x, wave = tid >> 6, lane = tid & 63;
    const int row0 = band * 32 + wave * 8;

    // 8 independent nontemporal 16B loads (128 B/lane in flight)
    const u32x4* ap = (const u32x4*)(adj + (size_t)b * NN * NN) + (size_t)row0 * 64 + lane;
    u32x4 av[8];
    #pragma unroll
    for (int j = 0; j < 8; ++j) av[j] = __builtin_nontemporal_load(&ap[j * 64]);

    // types for my 8 rows (wave-uniform)
    const int* ty = node_types + b * NN + row0;
    unsigned pcnt[4][8];
    #pragma unroll
    for (int c = 0; c < 4; ++c)
        #pragma unroll
        for (int q = 0; q < 8; ++q) pcnt[c][q] = 0;

    #pragma unroll
    for (int j = 0; j < 8; ++j) {
        unsigned t = (unsigned)__builtin_amdgcn_readfirstlane(ty[j]);
        unsigned sh = (t & 3u) * 8u;
        u32x4 a = av[j];
        switch (t >> 2) {                 // wave-uniform -> scalar branch
            case 0: pcnt[0][0] += a.x << sh; pcnt[1][0] += a.y << sh; pcnt[2][0] += a.z << sh; pcnt[3][0] += a.w << sh; break;
            case 1: pcnt[0][1] += a.x << sh; pcnt[1][1] += a.y << sh; pcnt[2][1] += a.z << sh; pcnt[3][1] += a.w << sh; break;
            case 2: pcnt[0][2] += a.x << sh; pcnt[1][2] += a.y << sh; pcnt[2][2] += a.z << sh; pcnt[3][2] += a.w << sh; break;
            case 3: pcnt[0][3] += a.x << sh; pcnt[1][3] += a.y << sh; pcnt[2][3] += a.z << sh; pcnt[3][3] += a.w << sh; break;
            case 4: pcnt[0][4] += a.x << sh; pcnt[1][4] += a.y << sh; pcnt[2][4] += a.z << sh; pcnt[3][4] += a.w << sh; break;
            case 5: pcnt[0][5] += a.x << sh; pcnt[1][5] += a.y << sh; pcnt[2][5] += a.z << sh; pcnt[3][5] += a.w << sh; break;
            case 6: pcnt[0][6] += a.x << sh; pcnt[1][6] += a.y << sh; pcnt[2][6] += a.z << sh; pcnt[3][6] += a.w << sh; break;
            default: pcnt[0][7] += a.x << sh; pcnt[1][7] += a.y << sh; pcnt[2][7] += a.z << sh; pcnt[3][7] += a.w << sh; break;
        }
    }

    // block combine: [wave][q][col] (lane stride 4 words -> 4-way bank alias, cheap)
    #pragma unroll
    for (int c = 0; c < 4; ++c) {
        int col = lane * 4 + c;
        #pragma unroll
        for (int q = 0; q < 8; ++q) pc[wave][q][col] = pcnt[c][q];
    }
    __syncthreads();

    // one packed-byte atomic per (col, q); total per cell <= 255 -> no carry
    unsigned* dst = cnt + ((size_t)b * NN + tid) * 8;
    #pragma unroll
    for (int q = 0; q < 8; ++q) {
        unsigned s = pc[0][q][tid] + pc[1][q][tid] + pc[2][q][tid] + pc[3][q][tid];
        atomicAdd(&dst[q], s);
    }
}

// ---------------- Kernel M: MFMA + GRU + readout ----------------------------
__global__ void __launch_bounds__(256) dvae_main(
    const int* __restrict__ node_types, const unsigned* __restrict__ cntw,
    const short* __restrict__ TABB, const short* __restrict__ GIT2,
    const float* __restrict__ b_hh,
    const float* __restrict__ W1, const float* __restrict__ b1,
    const float* __restrict__ W2, const float* __restrict__ b2,
    float* __restrict__ out)
{
    __shared__ unsigned cntA[NN * 20];    // 20 KB bf16 count pairs, row = 16 u32 + 4 pad
    __shared__ short GITs[NVT * 512];     // 32 KB [t][h][4] = {r,z,n,0}
    __shared__ int types_s[NN];
    __shared__ float hg_s[HS];

    const int b = blockIdx.x, tid = threadIdx.x;   // 256 thr = 4 waves
    const int wave = tid >> 6, lane = tid & 63;
    const int quad = lane >> 4, col = lane & 15;

    types_s[tid] = node_types[b * NN + tid];

    // load packed counts (8 u32) -> exact bf16 pairs in padded LDS rows
    {
        const uint4* src = (const uint4*)(cntw + ((size_t)b * NN + tid) * 8);
        uint4 a0 = src[0], a1 = src[1];
        unsigned acc8[8] = {a0.x, a0.y, a0.z, a0.w, a1.x, a1.y, a1.z, a1.w};
        #pragma unroll
        for (int q = 0; q < 8; ++q) {
            unsigned u = acc8[q];
            float f0 = (float)(u & 0xFF),         f1 = (float)((u >> 8) & 0xFF);
            float f2 = (float)((u >> 16) & 0xFF), f3 = (float)((u >> 24) & 0xFF);
            cntA[tid * 20 + 2 * q]     = (__float_as_uint(f0) >> 16) | (__float_as_uint(f1) & 0xFFFF0000u);
            cntA[tid * 20 + 2 * q + 1] = (__float_as_uint(f2) >> 16) | (__float_as_uint(f3) & 0xFFFF0000u);
        }
    }
    // stage GIT2 -> LDS (8192 u32, coalesced uint4)
    {
        const uint4* src = (const uint4*)GIT2;
        uint4* dst = (uint4*)GITs;
        #pragma unroll
        for (int i = 0; i < 8; ++i) dst[i * 256 + tid] = src[i * 256 + tid];
    }
    // B fragments: wave w owns h in [w*32, w*32+32): r,z,n gates + Hpre, 2 tiles each
    bf16x8 bfrag[8];
    #pragma unroll
    for (int i = 0; i < 8; ++i) {
        int gate = i >> 1, sub = (i & 1) * 16;
        int jb = (gate < 3 ? gate * 128 : 384) + wave * 32 + sub;
        bfrag[i] = *(const bf16x8*)(TABB + (jb + col) * 32 + quad * 8);
    }
    const int h0 = wave * 32 + col;
    const float bhn0 = b_hh[256 + h0], bhn1 = b_hh[256 + h0 + 16];
    float hg0 = 0.f, hg1 = 0.f;
    __syncthreads();

    // 16 m-tiles, barrier-free in-register GRU epilogue
    for (int m = 0; m < 16; ++m) {
        bf16x8 afrag = *(const bf16x8*)(cntA + (m * 16 + col) * 20 + quad * 4);
        f32x4 acc[8];
        #pragma unroll
        for (int i = 0; i < 8; ++i)
            acc[i] = __builtin_amdgcn_mfma_f32_16x16x32_bf16(
                afrag, bfrag[i], (f32x4){0.f, 0.f, 0.f, 0.f}, 0, 0, 0);
        // C/D: col = n (h), row = quad*4 + r (v)
        #pragma unroll
        for (int r = 0; r < 4; ++r) {
            int vv = m * 16 + quad * 4 + r;
            int tv = types_s[vv];
            float msk = (vv >= 1 && vv < NN - 1) ? 1.f : 0.f;
            {   // h = h0
                s16x4 gg = *(const s16x4*)(GITs + (tv * 128 + h0) * 4);
                float rr = sigm(bs2f(gg[0]) + acc[0][r]);
                float zz = sigm(bs2f(gg[1]) + acc[2][r]);
                float x2 = bs2f(gg[2]) + rr * (acc[4][r] + bhn0);
                float nt = 1.f - 2.f * __builtin_amdgcn_rcpf(1.f + __expf(2.f * x2));
                hg0 += msk * ((1.f - zz) * nt + zz * acc[6][r]);
            }
            {   // h = h0 + 16
                s16x4 gg = *(const s16x4*)(GITs + (tv * 128 + h0 + 16) * 4);
                float rr = sigm(bs2f(gg[0]) + acc[1][r]);
                float zz = sigm(bs2f(gg[1]) + acc[3][r]);
                float x2 = bs2f(gg[2]) + rr * (acc[5][r] + bhn1);
                float nt = 1.f - 2.f * __builtin_amdgcn_rcpf(1.f + __expf(2.f * x2));
                hg1 += msk * ((1.f - zz) * nt + zz * acc[7][r]);
            }
        }
    }
    // reduce across quads (lane ^16, ^32 share h0)
    hg0 += __shfl_xor(hg0, 16); hg0 += __shfl_xor(hg0, 32);
    hg1 += __shfl_xor(hg1, 16); hg1 += __shfl_xor(hg1, 32);
    if (lane < 16) { hg_s[h0] = hg0; hg_s[h0 + 16] = hg1; }
    __syncthreads();

    // fused readout: mu (tid<64) / logvar (64<=tid<128)
    if (tid < 128) {
        int which = tid >> 6, zz = tid & 63;
        const float* W = which ? W2 : W1;
        float acc2 = which ? b2[zz] : b1[zz];
        const float4* Wv = (const float4*)(W + zz * HS);
        #pragma unroll
        for (int i = 0; i < 32; ++i) {
            float4 ww = Wv[i];
            acc2 += hg_s[4 * i] * ww.x + hg_s[4 * i + 1] * ww.y
                  + hg_s[4 * i + 2] * ww.z + hg_s[4 * i + 3] * ww.w;
        }
        out[which * 32768 + b * 64 + zz] = acc2;
    }
}

extern "C" void kernel_launch(void* const* d_in, const int* in_sizes, int n_in,
                              void* d_out, int out_size, void* d_ws, size_t ws_size,
                              hipStream_t stream)
{
    const int* node_types = (const int*)d_in[0];
    const int* adj        = (const int*)d_in[1];
    const float* W_ih = (const float*)d_in[2];
    const float* W_hh = (const float*)d_in[3];
    const float* b_ih = (const float*)d_in[4];
    const float* b_hh = (const float*)d_in[5];
    const float* Wg   = (const float*)d_in[6];
    const float* bg   = (const float*)d_in[7];
    const float* Wm   = (const float*)d_in[8];
    const float* W1   = (const float*)d_in[9];
    const float* b1   = (const float*)d_in[10];
    const float* W2   = (const float*)d_in[11];
    const float* b2   = (const float*)d_in[12];

    char* ws = (char*)d_ws;
    short* TABB = (short*)(ws + TABB_OFF);
    short* GIT2 = (short*)(ws + GIT2_OFF);
    unsigned* cnt = (unsigned*)(ws + CNT_OFF);
    float* out  = (float*)d_out;

    zero_cnt<<<dim3(1024), dim3(256), 0, stream>>>((uint4*)cnt);
    build_tables<<<dim3(32), dim3(512), 0, stream>>>(W_ih, W_hh, b_ih, b_hh, Wg, bg, Wm, TABB, GIT2);
    hist<<<dim3(4096), dim3(256), 0, stream>>>(node_types, adj, cnt);
    dvae_main<<<dim3(512), dim3(256), 0, stream>>>(node_types, cnt, TABB, GIT2, b_hh, W1, b1, W2, b2, out);
}